// Round 1
// 372.765 us; speedup vs baseline: 1.0513x; 1.0513x over previous
//
// R9: slc_swa_v8 — one wave per (t,hkv): no barriers, no cross-wave merge.
// cmp+topk+sel+swa all sequential in a single wave with one online-softmax
// accumulator set; gates folded at finalize. vcb stored transposed [d][n]
// so cmp PV B-frag is a single shortx8 load. Heavy-t blocks launch first.
// GEMMs / casts / rope unchanged from R8.
#include <hip/hip_runtime.h>
#include <hip/hip_bf16.h>
#include <math.h>

#define T_SEQ 1024
#define NH    64
#define NKV   4
#define DH    64
#define GQ    16
#define BSZ   64
#define NBLK  16
#define SSEL  8
#define WWIN  512
#define SCL   0.125f
#define NEGF  -1e30f
#define KVGS  768

typedef float  floatx4 __attribute__((ext_vector_type(4)));
typedef short  shortx8 __attribute__((ext_vector_type(8)));

__device__ __forceinline__ ushort f2bf(float f) {
  union { float f; unsigned u; } v; v.f = f;
  unsigned r = v.u + 0x7FFF + ((v.u >> 16) & 1);
  return (ushort)(r >> 16);
}
__device__ __forceinline__ float bf2f(ushort u) {
  union { unsigned u; float f; } v; v.u = ((unsigned)u) << 16;
  return v.f;
}
__device__ __forceinline__ void gld_lds16(const ushort* g, ushort* l) {
  __builtin_amdgcn_global_load_lds((const __attribute__((address_space(1))) void*)g,
                                   (__attribute__((address_space(3))) void*)l, 16, 0, 0);
}

// ---------------- cast fp32 -> bf16 ----------------
__global__ void cast_x(const float* __restrict__ in, ushort* __restrict__ out, int n4) {
  int i = blockIdx.x * blockDim.x + threadIdx.x;
  if (i >= n4) return;
  float4 f = ((const float4*)in)[i];
  ushort4 u;
  u.x = f2bf(f.x); u.y = f2bf(f.y); u.z = f2bf(f.z); u.w = f2bf(f.w);
  ((ushort4*)out)[i] = u;
}

// ---------------- cast+transpose fp32 [K][N] -> bf16 [N][K] ----------------
__global__ __launch_bounds__(256) void cast_tr(const float* __restrict__ in,
                                               ushort* __restrict__ out, int K, int N) {
  __shared__ float tile[32][33];
  int k0 = blockIdx.y * 32, n0 = blockIdx.x * 32;
  int tx = threadIdx.x & 31, ty = threadIdx.x >> 5;
#pragma unroll
  for (int r = 0; r < 32; r += 8)
    tile[ty + r][tx] = in[(size_t)(k0 + ty + r) * N + n0 + tx];
  __syncthreads();
#pragma unroll
  for (int r = 0; r < 32; r += 8)
    out[(size_t)(n0 + ty + r) * K + k0 + tx] = f2bf(tile[tx][ty + r]);
}

// ---------------- fused Wk|Wv|Wg cast+transpose into Wkvg[704][2048] ----------------
__global__ __launch_bounds__(256) void cast_tr_kvg(const float* __restrict__ Wk,
                                                   const float* __restrict__ Wv,
                                                   const float* __restrict__ Wg,
                                                   ushort* __restrict__ out) {
  __shared__ float tile[32][33];
  int n0 = blockIdx.x * 32;           // 0..672
  int k0 = blockIdx.y * 32;
  const float* src; int coff, Nsrc;
  if (n0 < 256)      { src = Wk; coff = n0;       Nsrc = 256; }
  else if (n0 < 512) { src = Wv; coff = n0 - 256; Nsrc = 256; }
  else               { src = Wg; coff = n0 - 512; Nsrc = 192; }
  int tx = threadIdx.x & 31, ty = threadIdx.x >> 5;
#pragma unroll
  for (int r = 0; r < 32; r += 8)
    tile[ty + r][tx] = src[(size_t)(k0 + ty + r) * Nsrc + coff + tx];
  __syncthreads();
#pragma unroll
  for (int r = 0; r < 32; r += 8)
    out[(size_t)(n0 + ty + r) * 2048 + k0 + tx] = f2bf(tile[tx][ty + r]);
}

// ---------------- bf16 GEMM BM64 BN128 BK64, fp32 C ----------------
__global__ __launch_bounds__(256) void gemm_bf16_64(const ushort* __restrict__ A,
                                                    const ushort* __restrict__ Bt,
                                                    float* __restrict__ C,
                                                    int M, int N, int K) {
  __shared__ ushort As[64 * 64];
  __shared__ ushort Bs[128 * 64];
  int tid = threadIdx.x, wv = tid >> 6, lane = tid & 63;
  int m0 = blockIdx.y * 64, n0 = blockIdx.x * 128;
  int l15 = lane & 15, l4 = lane >> 4;
  floatx4 acc[4][2];
#pragma unroll
  for (int i = 0; i < 4; ++i) { acc[i][0] = 0.0f; acc[i][1] = 0.0f; }
  for (int k0 = 0; k0 < K; k0 += 64) {
#pragma unroll
    for (int it = 0; it < 2; ++it) {
      int ci = (it * 4 + wv) * 64 + lane;
      gld_lds16(A + (size_t)(m0 + (ci >> 3)) * K + k0 + (ci & 7) * 8,
                As + (size_t)(it * 4 + wv) * 512);
    }
#pragma unroll
    for (int it = 0; it < 4; ++it) {
      int ci = (it * 4 + wv) * 64 + lane;
      gld_lds16(Bt + (size_t)(n0 + (ci >> 3)) * K + k0 + (ci & 7) * 8,
                Bs + (size_t)(it * 4 + wv) * 512);
    }
    __syncthreads();
#pragma unroll
    for (int ks = 0; ks < 2; ++ks) {
      shortx8 af[4], bf[2];
#pragma unroll
      for (int i = 0; i < 4; ++i)
        af[i] = *(const shortx8*)&As[(i * 16 + l15) * 64 + ks * 32 + l4 * 8];
#pragma unroll
      for (int j = 0; j < 2; ++j)
        bf[j] = *(const shortx8*)&Bs[(wv * 32 + j * 16 + l15) * 64 + ks * 32 + l4 * 8];
#pragma unroll
      for (int i = 0; i < 4; ++i)
#pragma unroll
        for (int j = 0; j < 2; ++j)
          acc[i][j] = __builtin_amdgcn_mfma_f32_16x16x32_bf16(af[i], bf[j], acc[i][j], 0, 0, 0);
    }
    __syncthreads();
  }
#pragma unroll
  for (int i = 0; i < 4; ++i)
#pragma unroll
    for (int j = 0; j < 2; ++j)
#pragma unroll
      for (int r = 0; r < 4; ++r)
        C[(size_t)(m0 + i * 16 + l4 * 4 + r) * N + n0 + wv * 32 + j * 16 + l15] = acc[i][j][r];
}

// ---------------- same, bf16 C (q projection) ----------------
__global__ __launch_bounds__(256) void gemm_bf16_64b(const ushort* __restrict__ A,
                                                     const ushort* __restrict__ Bt,
                                                     ushort* __restrict__ C,
                                                     int M, int N, int K) {
  __shared__ ushort As[64 * 64];
  __shared__ ushort Bs[128 * 64];
  int tid = threadIdx.x, wv = tid >> 6, lane = tid & 63;
  int m0 = blockIdx.y * 64, n0 = blockIdx.x * 128;
  int l15 = lane & 15, l4 = lane >> 4;
  floatx4 acc[4][2];
#pragma unroll
  for (int i = 0; i < 4; ++i) { acc[i][0] = 0.0f; acc[i][1] = 0.0f; }
  for (int k0 = 0; k0 < K; k0 += 64) {
#pragma unroll
    for (int it = 0; it < 2; ++it) {
      int ci = (it * 4 + wv) * 64 + lane;
      gld_lds16(A + (size_t)(m0 + (ci >> 3)) * K + k0 + (ci & 7) * 8,
                As + (size_t)(it * 4 + wv) * 512);
    }
#pragma unroll
    for (int it = 0; it < 4; ++it) {
      int ci = (it * 4 + wv) * 64 + lane;
      gld_lds16(Bt + (size_t)(n0 + (ci >> 3)) * K + k0 + (ci & 7) * 8,
                Bs + (size_t)(it * 4 + wv) * 512);
    }
    __syncthreads();
#pragma unroll
    for (int ks = 0; ks < 2; ++ks) {
      shortx8 af[4], bf[2];
#pragma unroll
      for (int i = 0; i < 4; ++i)
        af[i] = *(const shortx8*)&As[(i * 16 + l15) * 64 + ks * 32 + l4 * 8];
#pragma unroll
      for (int j = 0; j < 2; ++j)
        bf[j] = *(const shortx8*)&Bs[(wv * 32 + j * 16 + l15) * 64 + ks * 32 + l4 * 8];
#pragma unroll
      for (int i = 0; i < 4; ++i)
#pragma unroll
        for (int j = 0; j < 2; ++j)
          acc[i][j] = __builtin_amdgcn_mfma_f32_16x16x32_bf16(af[i], bf[j], acc[i][j], 0, 0, 0);
    }
    __syncthreads();
  }
#pragma unroll
  for (int i = 0; i < 4; ++i)
#pragma unroll
    for (int j = 0; j < 2; ++j)
#pragma unroll
      for (int r = 0; r < 4; ++r)
        C[(size_t)(m0 + i * 16 + l4 * 4 + r) * N + n0 + wv * 32 + j * 16 + l15] =
            f2bf(acc[i][j][r]);
}

// ---------------- bf16 GEMM BM64 BN64 (out projection), fp32 C ----------------
__global__ __launch_bounds__(256) void gemm_out64(const ushort* __restrict__ A,
                                                  const ushort* __restrict__ Bt,
                                                  float* __restrict__ C,
                                                  int M, int N, int K) {
  __shared__ ushort As[64 * 64];
  __shared__ ushort Bs[64 * 64];
  int tid = threadIdx.x, wv = tid >> 6, lane = tid & 63;
  int m0 = blockIdx.y * 64, n0 = blockIdx.x * 64;
  int l15 = lane & 15, l4 = lane >> 4;
  floatx4 acc[4];
#pragma unroll
  for (int i = 0; i < 4; ++i) acc[i] = 0.0f;
  for (int k0 = 0; k0 < K; k0 += 64) {
#pragma unroll
    for (int it = 0; it < 2; ++it) {
      int ci = (it * 4 + wv) * 64 + lane;
      gld_lds16(A + (size_t)(m0 + (ci >> 3)) * K + k0 + (ci & 7) * 8,
                As + (size_t)(it * 4 + wv) * 512);
      gld_lds16(Bt + (size_t)(n0 + (ci >> 3)) * K + k0 + (ci & 7) * 8,
                Bs + (size_t)(it * 4 + wv) * 512);
    }
    __syncthreads();
#pragma unroll
    for (int ks = 0; ks < 2; ++ks) {
      shortx8 af[4], bf;
#pragma unroll
      for (int i = 0; i < 4; ++i)
        af[i] = *(const shortx8*)&As[(i * 16 + l15) * 64 + ks * 32 + l4 * 8];
      bf = *(const shortx8*)&Bs[(wv * 16 + l15) * 64 + ks * 32 + l4 * 8];
#pragma unroll
      for (int i = 0; i < 4; ++i)
        acc[i] = __builtin_amdgcn_mfma_f32_16x16x32_bf16(af[i], bf, acc[i], 0, 0, 0);
    }
    __syncthreads();
  }
#pragma unroll
  for (int i = 0; i < 4; ++i)
#pragma unroll
    for (int r = 0; r < 4; ++r)
      C[(size_t)(m0 + i * 16 + l4 * 4 + r) * N + n0 + wv * 16 + l15] = acc[i][r];
}

// ---------------- RoPE on bf16 q ----------------
__global__ void rope_bq(ushort* __restrict__ qb) {
  int idx = blockIdx.x * blockDim.x + threadIdx.x;
  if (idx >= T_SEQ * NH * 32) return;
  int i = idx & 31;
  int h = (idx >> 5) & 63;
  int t = idx / (32 * NH);
  float inv = __expf(-(float)i * 0.28782313662425575f);
  float f = (float)t * inv;
  float s, c;
  __sincosf(f, &s, &c);
  ushort* p = qb + ((size_t)t * NH + h) * DH;
  float x1 = bf2f(p[i]), x2 = bf2f(p[i + 32]);
  p[i]      = f2bf(x1 * c - x2 * s);
  p[i + 32] = f2bf(x1 * s + x2 * c);
}

// ---------------- RoPE on fp32 k + write bf16 kb (fused) ----------------
__global__ void rope_kb(float* __restrict__ kvg, ushort* __restrict__ kb) {
  int idx = blockIdx.x * blockDim.x + threadIdx.x;
  if (idx >= T_SEQ * NKV * 32) return;
  int i = idx & 31;
  int h = (idx >> 5) & 3;
  int t = idx / (32 * NKV);
  float inv = __expf(-(float)i * 0.28782313662425575f);
  float f = (float)t * inv;
  float s, c;
  __sincosf(f, &s, &c);
  float* p = kvg + (size_t)t * KVGS + h * DH;
  float x1 = p[i], x2 = p[i + 32];
  float r1 = x1 * c - x2 * s, r2 = x1 * s + x2 * c;
  p[i] = r1; p[i + 32] = r2;
  ushort* kp = kb + (size_t)t * 256 + h * DH;
  kp[i] = f2bf(r1); kp[i + 32] = f2bf(r2);
}

// ---------------- V -> bf16 transposed vtg[d(256)][t(1024)] ----------------
__global__ __launch_bounds__(256) void vt_tr(const float* __restrict__ kvg,
                                             ushort* __restrict__ vtg) {
  __shared__ float tile[32][33];
  int t0 = blockIdx.x * 32, d0 = blockIdx.y * 32;
  int tx = threadIdx.x & 31, ty = threadIdx.x >> 5;
#pragma unroll
  for (int r = 0; r < 32; r += 8)
    tile[ty + r][tx] = kvg[(size_t)(t0 + ty + r) * KVGS + 256 + d0 + tx];
  __syncthreads();
#pragma unroll
  for (int r = 0; r < 32; r += 8)
    vtg[(size_t)(d0 + ty + r) * T_SEQ + t0 + tx] = f2bf(tile[tx][ty + r]);
}

// ---------------- block means -> bf16 kcb[n][256], vcbT[d(256)][n(16)] ----------------
__global__ void cmp_mean(const float* __restrict__ kvg,
                         ushort* __restrict__ kcb, ushort* __restrict__ vcbT) {
  int idx = blockIdx.x * blockDim.x + threadIdx.x;
  if (idx >= NBLK * NKV * DH) return;
  int d = idx & 63, hkv = (idx >> 6) & 3, n = idx >> 8;
  float sk = 0.f, sv = 0.f;
  for (int j = 0; j < BSZ; ++j) {
    size_t row = (size_t)(n * BSZ + j) * KVGS;
    sk += kvg[row + hkv * DH + d];
    sv += kvg[row + 256 + hkv * DH + d];
  }
  kcb[idx] = f2bf(sk * (1.0f / 64.0f));
  vcbT[(size_t)(hkv * 64 + d) * 16 + n] = f2bf(sv * (1.0f / 64.0f));
}

// ---------------- fused cmp + topk + slc + swa: ONE WAVE per (t,hkv) (v8) ----------------
__global__ __launch_bounds__(64, 4) void slc_swa_v8(
    const ushort* __restrict__ qb, const float* __restrict__ kvg,
    const ushort* __restrict__ kb, const ushort* __restrict__ vtg,
    const ushort* __restrict__ kcb, const ushort* __restrict__ vcbT,
    ushort* __restrict__ obuf) {
  __shared__ __align__(16) ushort PtW[16 * 72];   // per-wave P staging, pitch 72

  int lane = threadIdx.x;
  int t = (T_SEQ - 1) - (int)(blockIdx.x >> 2);   // heavy t first
  int hkv = blockIdx.x & 3;
  int l15 = lane & 15, quad = lane >> 4;
  const float INF = __builtin_inff();

  const ushort* qrow = qb + ((size_t)t * NH + hkv * GQ + l15) * DH;
  shortx8 qf0 = *(const shortx8*)(qrow + quad * 8);
  shortx8 qf1 = *(const shortx8*)(qrow + 32 + quad * 8);

  int nv = (t >= 63) ? (((t - 63) >> 6) + 1) : 0;
  int cur = t >> 6;

  // gates: 12 consecutive floats cover this lane's 4 heads x 3 branches
  const float* gp = kvg + (size_t)t * KVGS + 512 + hkv * 48 + quad * 12;
  float4 ga = *(const float4*)gp;
  float4 gbv = *(const float4*)(gp + 4);
  float4 gcv = *(const float4*)(gp + 8);
  float g12[12] = {ga.x, ga.y, ga.z, ga.w, gbv.x, gbv.y, gbv.z, gbv.w,
                   gcv.x, gcv.y, gcv.z, gcv.w};
  float g_cmp[4], g_slc[4], g_swa[4];
#pragma unroll
  for (int r = 0; r < 4; ++r) {
    g_cmp[r] = 1.f / (1.f + __expf(-g12[r * 3 + 0]));
    g_slc[r] = 1.f / (1.f + __expf(-g12[r * 3 + 1]));
    g_swa[r] = 1.f / (1.f + __expf(-g12[r * 3 + 2]));
  }

  float fin[4][4];   // [dt][r] : head = quad*4+r, d = dt*16+l15
#pragma unroll
  for (int dt = 0; dt < 4; ++dt)
#pragma unroll
    for (int r = 0; r < 4; ++r) fin[dt][r] = 0.f;

  // ===== compressed attention + importance =====
  float imp_l = 0.f;
  if (nv > 0) {
    const ushort* kcp = kcb + l15 * 256 + hkv * 64 + quad * 8;
    shortx8 kcf0 = *(const shortx8*)kcp;
    shortx8 kcf1 = *(const shortx8*)(kcp + 32);
    floatx4 dc = 0.0f;
    dc = __builtin_amdgcn_mfma_f32_16x16x32_bf16(qf0, kcf0, dc, 0, 0, 0);
    dc = __builtin_amdgcn_mfma_f32_16x16x32_bf16(qf1, kcf1, dc, 0, 0, 0);
    bool cvalid = (l15 < nv);
    float p[4];
#pragma unroll
    for (int r = 0; r < 4; ++r) {
      float sv = cvalid ? dc[r] * SCL : NEGF;
      float mx = sv;
#pragma unroll
      for (int msk = 1; msk < 16; msk <<= 1) mx = fmaxf(mx, __shfl_xor(mx, msk, 64));
      float pv = __expf(sv - mx);
      float su = pv;
#pragma unroll
      for (int msk = 1; msk < 16; msk <<= 1) su += __shfl_xor(su, msk, 64);
      p[r] = pv / su;
      imp_l += p[r];
    }
    imp_l += __shfl_xor(imp_l, 16, 64);
    imp_l += __shfl_xor(imp_l, 32, 64);
    // gated P into PtW rows=head cols=block; zero cols 16..31 for the MFMA
    *(uint2*)&PtW[(lane >> 2) * 72 + 16 + (lane & 3) * 4] = make_uint2(0, 0);
#pragma unroll
    for (int r = 0; r < 4; ++r)
      PtW[(quad * 4 + r) * 72 + l15] = f2bf(p[r] * g_cmp[r]);
    shortx8 pA = *(const shortx8*)&PtW[l15 * 72 + quad * 8];
#pragma unroll
    for (int dt = 0; dt < 4; ++dt) {
      shortx8 vB = *(const shortx8*)&vcbT[(size_t)(hkv * 64 + dt * 16 + l15) * 16 +
                                          (quad & 1) * 8];
      floatx4 oc = 0.0f;
      oc = __builtin_amdgcn_mfma_f32_16x16x32_bf16(pA, vB, oc, 0, 0, 0);
#pragma unroll
      for (int r = 0; r < 4; ++r) fin[dt][r] = oc[r];
    }
  }

  // ===== online-softmax accumulators (shared by sel then swa) =====
  float m_[4], l_[4];
  floatx4 o_[4];
  auto reset_acc = [&]() {
#pragma unroll
    for (int r = 0; r < 4; ++r) { m_[r] = -INF; l_[r] = 0.f; }
#pragma unroll
    for (int dt = 0; dt < 4; ++dt) o_[dt] = 0.0f;
  };

  auto do_tile = [&](int b, bool is_swa) {
    int pos0 = b * BSZ;
    floatx4 dk[4];
#pragma unroll
    for (int kt = 0; kt < 4; ++kt) {
      int key = pos0 + kt * 16 + l15;
      const ushort* kr = &kb[(size_t)key * 256 + hkv * 64];
      shortx8 kf0 = *(const shortx8*)(kr + quad * 8);
      shortx8 kf1 = *(const shortx8*)(kr + 32 + quad * 8);
      floatx4 d = 0.0f;
      d = __builtin_amdgcn_mfma_f32_16x16x32_bf16(qf0, kf0, d, 0, 0, 0);
      d = __builtin_amdgcn_mfma_f32_16x16x32_bf16(qf1, kf1, d, 0, 0, 0);
      dk[kt] = d;
    }
#pragma unroll
    for (int kt = 0; kt < 4; ++kt) {
      int key = pos0 + kt * 16 + l15;
      bool valid = (key <= t) && (!is_swa || (key >= t - (WWIN - 1)));
#pragma unroll
      for (int r = 0; r < 4; ++r)
        dk[kt][r] = valid ? dk[kt][r] * SCL : NEGF;
    }
    float alpha[4], rs[4];
#pragma unroll
    for (int r = 0; r < 4; ++r) {
      float v = fmaxf(fmaxf(dk[0][r], dk[1][r]), fmaxf(dk[2][r], dk[3][r]));
#pragma unroll
      for (int msk = 1; msk < 16; msk <<= 1) v = fmaxf(v, __shfl_xor(v, msk, 64));
      float mn = fmaxf(m_[r], v);
      alpha[r] = __expf(m_[r] - mn);
      m_[r] = mn;
      rs[r] = 0.f;
    }
#pragma unroll
    for (int kt = 0; kt < 4; ++kt)
#pragma unroll
      for (int r = 0; r < 4; ++r) {
        float pv = __expf(dk[kt][r] - m_[r]);
        PtW[(quad * 4 + r) * 72 + kt * 16 + l15] = f2bf(pv);
        rs[r] += pv;
      }
#pragma unroll
    for (int r = 0; r < 4; ++r) {
#pragma unroll
      for (int msk = 1; msk < 16; msk <<= 1) rs[r] += __shfl_xor(rs[r], msk, 64);
      l_[r] = l_[r] * alpha[r] + rs[r];
    }
#pragma unroll
    for (int dt = 0; dt < 4; ++dt)
#pragma unroll
      for (int r = 0; r < 4; ++r)
        o_[dt][r] *= alpha[r];
    shortx8 pf0 = *(const shortx8*)&PtW[l15 * 72 + quad * 8];
    shortx8 pf1 = *(const shortx8*)&PtW[l15 * 72 + 32 + quad * 8];
#pragma unroll
    for (int dt = 0; dt < 4; ++dt) {
      const ushort* vr = &vtg[(size_t)(hkv * 64 + dt * 16 + l15) * T_SEQ + pos0];
      shortx8 vf0 = *(const shortx8*)(vr + quad * 8);
      shortx8 vf1 = *(const shortx8*)(vr + 32 + quad * 8);
      o_[dt] = __builtin_amdgcn_mfma_f32_16x16x32_bf16(pf0, vf0, o_[dt], 0, 0, 0);
      o_[dt] = __builtin_amdgcn_mfma_f32_16x16x32_bf16(pf1, vf1, o_[dt], 0, 0, 0);
    }
  };

  // ===== selection: top-8 argmax interleaved with sel tiles =====
  float tval;
  if (l15 > cur)                   tval = -INF;
  else if (l15 == 0 || l15 == cur) tval = INF;
  else                             tval = imp_l;

  reset_acc();
#pragma unroll 1
  for (int s = 0; s < SSEL; ++s) {
    float v = tval; int i = l15;
#pragma unroll
    for (int msk = 1; msk < 16; msk <<= 1) {
      float vo = __shfl_xor(v, msk, 64);
      int io = __shfl_xor(i, msk, 64);
      if (vo > v || (vo == v && io < i)) { v = vo; i = io; }
    }
    if (!(v > -INF)) break;        // remaining slots invalid (uniform)
    if (l15 == i) tval = -INF;     // remove winner
    do_tile(i, false);
  }
#pragma unroll
  for (int r = 0; r < 4; ++r) {
    float inv = g_slc[r] / l_[r];
#pragma unroll
    for (int dt = 0; dt < 4; ++dt) fin[dt][r] += o_[dt][r] * inv;
  }

  // ===== sliding window =====
  reset_acc();
  int lo = t - (WWIN - 1); if (lo < 0) lo = 0;
#pragma unroll 1
  for (int b = lo >> 6; b <= cur; ++b) do_tile(b, true);
#pragma unroll
  for (int r = 0; r < 4; ++r) {
    float inv = g_swa[r] / l_[r];
#pragma unroll
    for (int dt = 0; dt < 4; ++dt) fin[dt][r] += o_[dt][r] * inv;
  }

  // ===== write =====
  ushort* op = obuf + (size_t)t * 4096 + (size_t)(hkv * GQ + quad * 4) * 64 + l15;
#pragma unroll
  for (int r = 0; r < 4; ++r)
#pragma unroll
    for (int dt = 0; dt < 4; ++dt)
      op[r * 64 + dt * 16] = f2bf(fin[dt][r]);
}

extern "C" void kernel_launch(void* const* d_in, const int* in_sizes, int n_in,
                              void* d_out, int out_size, void* d_ws, size_t ws_size,
                              hipStream_t stream) {
  const float* x  = (const float*)d_in[0];
  const float* Wq = (const float*)d_in[1];
  const float* Wk = (const float*)d_in[2];
  const float* Wv = (const float*)d_in[3];
  const float* Wg = (const float*)d_in[4];
  const float* Wo = (const float*)d_in[5];
  float* out = (float*)d_out;

  char* p = (char*)d_ws;
  ushort* xb    = (ushort*)p;  p += (size_t)1024 * 2048 * 2;
  ushort* WT    = (ushort*)p;  p += (size_t)4096 * 2048 * 2;   // WqT, later WoT
  ushort* Wkvg  = (ushort*)p;  p += (size_t)768  * 2048 * 2;
  ushort* qbh   = (ushort*)p;  p += (size_t)1024 * 4096 * 2;
  float*  kvg   = (float*)p;   p += (size_t)1024 * KVGS * 4;
  ushort* obuf  = (ushort*)p;  p += (size_t)1024 * 4096 * 2;
  ushort* kcb   = (ushort*)p;  p += (size_t)4096 * 2;
  ushort* vcbT  = (ushort*)p;  p += (size_t)4096 * 2;
  ushort* kb    = (ushort*)p;  p += (size_t)1024 * 256 * 2;
  ushort* vtg   = (ushort*)p;  p += (size_t)256 * 1024 * 2;

  hipMemsetAsync(Wkvg + (size_t)704 * 2048, 0, (size_t)64 * 2048 * 2, stream);

  cast_x<<<2048, 256, 0, stream>>>(x, xb, 1024 * 2048 / 4);
  cast_tr<<<dim3(4096 / 32, 2048 / 32), 256, 0, stream>>>(Wq, WT, 2048, 4096);
  cast_tr_kvg<<<dim3(704 / 32, 2048 / 32), 256, 0, stream>>>(Wk, Wv, Wg, Wkvg);

  gemm_bf16_64b<<<dim3(4096 / 128, 1024 / 64), 256, 0, stream>>>(xb, WT, qbh, 1024, 4096, 2048);
  gemm_bf16_64<<<dim3(KVGS / 128, 1024 / 64), 256, 0, stream>>>(xb, Wkvg, kvg, 1024, KVGS, 2048);

  rope_bq<<<(T_SEQ * NH * 32 + 255) / 256, 256, 0, stream>>>(qbh);
  rope_kb<<<(T_SEQ * NKV * 32 + 255) / 256, 256, 0, stream>>>(kvg, kb);

  vt_tr<<<dim3(T_SEQ / 32, 256 / 32), 256, 0, stream>>>(kvg, vtg);
  cmp_mean<<<(NBLK * NKV * DH + 255) / 256, 256, 0, stream>>>(kvg, kcb, vcbT);

  slc_swa_v8<<<T_SEQ * NKV, 64, 0, stream>>>(qbh, kvg, kb, vtg, kcb, vcbT, obuf);

  cast_tr<<<dim3(2048 / 32, 4096 / 32), 256, 0, stream>>>(Wo, WT, 4096, 2048);
  gemm_out64<<<dim3(2048 / 64, 1024 / 64), 256, 0, stream>>>(obuf, WT, out, 1024, 2048, 4096);
}